// Round 15
// baseline (464.360 us; speedup 1.0000x reference)
//
#include <hip/hip_runtime.h>
#include <cstdint>

#define B_    16
#define L_    512
#define D_    768
#define DFF_  3072
#define DLLM_ 4096
#define E_    8

typedef unsigned short ushort_t;
typedef __attribute__((ext_vector_type(4))) float accfrag_t;
typedef __attribute__((ext_vector_type(8))) short bfrag_t;

typedef __attribute__((address_space(3))) uint32_t lds_u32;
typedef __attribute__((address_space(1))) uint32_t glb_u32;

__device__ inline void gload16(const void* g, void* l) {
  __builtin_amdgcn_global_load_lds((const glb_u32*)(uintptr_t)g,
                                   (lds_u32*)(uint32_t)(uintptr_t)l, 16, 0, 0);
}

__device__ inline ushort_t f2bf(float f) {
  uint32_t u = __float_as_uint(f);
  return (ushort_t)((u + 0x7FFFu + ((u >> 16) & 1u)) >> 16);  // RNE
}
__device__ inline float bf2f(ushort_t v) { return __uint_as_float(((uint32_t)v) << 16); }

#define MFMA16(a, b, c) __builtin_amdgcn_mfma_f32_16x16x32_bf16(a, b, c, 0, 0, 0)

#define GATE4 asm volatile("s_waitcnt vmcnt(4)" ::: "memory");
#define BAR_  { asm volatile("" ::: "memory"); __builtin_amdgcn_s_barrier(); \
                asm volatile("" ::: "memory"); }

// ---------------------------------------------------------------------------
// gemm1 (K=768): m201-style 8-phase 256x256 tile, BK=64, 512 thr / 8 waves,
// 2 LDS dbufs x (A 32KB + B 32KB) = 128KB, 1 block/CU.
// Wave output = two 64-row groups (one per A-half: rows mq*128+wm*64) x two
// 32-col groups (one per B-half: cols nq*128+wn*32) -> P0 first-touches
// exactly halves {A0,B0}, P1 -> A1, P2 -> B1, P3 -> none.
// Phase = { ds_read this phase's frags ; stage 1 half of tile t+1 ;
//           [gate vmcnt(4)] ; s_barrier ; setprio(1) 16 MFMA setprio(0) ;
//           s_barrier }   -- reads issue BEFORE the barrier, so their LDS
// latency hides in the barrier wait (r10's failure had reads after it).
// Gate accounting (2 loads/half, in-order retire; stages during t are for
// t+1 in order Ah0,Bh0,Ah1,Bh1):
//   P0 reads Ah0,Bh0(t) [issued (t-1).P0/P1]: after Bh0 come Ah1,Bh1 (4) ->
//     covered by (t-1).P3's GATE4.
//   P1 reads Ah1(t) [(t-1).P2]: after it Bh1(t), Ah0(t+1) (4) -> P0's GATE4.
//   P2 reads Bh1(t) [(t-1).P3]: after it Ah0',Bh0' (4) -> P1's GATE4.
//   P3 reads nothing -> no gate needed at P2.
// WAR: stage at t.Pi writes buf (t+1)&1, whose last readers ran at t-1 and
// are separated by >=2 barriers.  Last tile: stages disabled, gates trivial.
// Swizzle (both sides, measured 0 conflicts): 16B chunk c of a 128B row
// stored at c ^ (row&7); folded into pre-swizzled global source (linear LDS
// dest) and ds_read offsets.
// ---------------------------------------------------------------------------
template <int KT>
__device__ __forceinline__ void gemm8p(const char* gA, const char* gB,
                                       char* sm, accfrag_t acc[2][2][4][2]) {
  const int tid = threadIdx.x;
  const int lane = tid & 63;
  const int w = tid >> 6, wm = (w >> 2) & 1, wn = w & 3;
  const int LDB = KT * 128;

  const int R0 = tid >> 3;  // 0..63
  const int swz = (((tid & 7) ^ (R0 & 7)) << 4);
  const char* srcA = gA + (size_t)R0 * LDB + swz;
  const char* srcB = gB + (size_t)R0 * LDB + swz;
  const int dl = tid * 16;

  const int l15 = lane & 15, l7 = lane & 7, lhi = lane >> 4;
  const int c0 = ((lhi ^ l7) << 4), c1 = (((4 + lhi) ^ l7) << 4);
  const int aB = (wm * 64 + l15) * 128;           // within A-half
  const int bB = 32768 + (wn * 32 + l15) * 128;   // within B-half (base incl. B offset)

  auto STG_A = [&](int T, int H) {
    char* d = sm + ((T & 1) << 16) + (H << 14) + dl;
    const char* s = srcA + (size_t)(H * 128) * LDB + (size_t)T * 128;
    gload16(s, d);
    gload16(s + (size_t)64 * LDB, d + 8192);
  };
  auto STG_B = [&](int T, int H) {
    char* d = sm + ((T & 1) << 16) + 32768 + (H << 14) + dl;
    const char* s = srcB + (size_t)(H * 128) * LDB + (size_t)T * 128;
    gload16(s, d);
    gload16(s + (size_t)64 * LDB, d + 8192);
  };

  bfrag_t a0f[4][2], a1f[4][2], bf0[2][2], bf1[2][2];

  STG_A(0, 0); STG_B(0, 0); STG_A(0, 1); STG_B(0, 1);
  GATE4 BAR_

#pragma unroll 1
  for (int t = 0; t < KT; ++t) {
    const char* bu = sm + ((t & 1) << 16);
    const bool st = (t + 1 < KT);
    // ---- P0: read A-half0 + B-half0; stage Ah0(t+1); MFMA (mq0,nq0)
#pragma unroll
    for (int mf = 0; mf < 4; ++mf) {
      a0f[mf][0] = *(const bfrag_t*)(bu + aB + mf * 2048 + c0);
      a0f[mf][1] = *(const bfrag_t*)(bu + aB + mf * 2048 + c1);
    }
#pragma unroll
    for (int nf = 0; nf < 2; ++nf) {
      bf0[nf][0] = *(const bfrag_t*)(bu + bB + nf * 2048 + c0);
      bf0[nf][1] = *(const bfrag_t*)(bu + bB + nf * 2048 + c1);
    }
    if (st) STG_A(t + 1, 0);
    GATE4 BAR_
    __builtin_amdgcn_s_setprio(1);
#pragma unroll
    for (int mf = 0; mf < 4; ++mf)
#pragma unroll
      for (int nf = 0; nf < 2; ++nf) {
        acc[0][0][mf][nf] = MFMA16(a0f[mf][0], bf0[nf][0], acc[0][0][mf][nf]);
        acc[0][0][mf][nf] = MFMA16(a0f[mf][1], bf0[nf][1], acc[0][0][mf][nf]);
      }
    __builtin_amdgcn_s_setprio(0);
    BAR_
    // ---- P1: read A-half1; stage Bh0(t+1); MFMA (mq1,nq0)
#pragma unroll
    for (int mf = 0; mf < 4; ++mf) {
      a1f[mf][0] = *(const bfrag_t*)(bu + 16384 + aB + mf * 2048 + c0);
      a1f[mf][1] = *(const bfrag_t*)(bu + 16384 + aB + mf * 2048 + c1);
    }
    if (st) STG_B(t + 1, 0);
    GATE4 BAR_
    __builtin_amdgcn_s_setprio(1);
#pragma unroll
    for (int mf = 0; mf < 4; ++mf)
#pragma unroll
      for (int nf = 0; nf < 2; ++nf) {
        acc[1][0][mf][nf] = MFMA16(a1f[mf][0], bf0[nf][0], acc[1][0][mf][nf]);
        acc[1][0][mf][nf] = MFMA16(a1f[mf][1], bf0[nf][1], acc[1][0][mf][nf]);
      }
    __builtin_amdgcn_s_setprio(0);
    BAR_
    // ---- P2: read B-half1; stage Ah1(t+1); MFMA (mq1,nq1)  (no gate)
#pragma unroll
    for (int nf = 0; nf < 2; ++nf) {
      bf1[nf][0] = *(const bfrag_t*)(bu + 16384 + bB + nf * 2048 + c0);
      bf1[nf][1] = *(const bfrag_t*)(bu + 16384 + bB + nf * 2048 + c1);
    }
    if (st) STG_A(t + 1, 1);
    BAR_
    __builtin_amdgcn_s_setprio(1);
#pragma unroll
    for (int mf = 0; mf < 4; ++mf)
#pragma unroll
      for (int nf = 0; nf < 2; ++nf) {
        acc[1][1][mf][nf] = MFMA16(a1f[mf][0], bf1[nf][0], acc[1][1][mf][nf]);
        acc[1][1][mf][nf] = MFMA16(a1f[mf][1], bf1[nf][1], acc[1][1][mf][nf]);
      }
    __builtin_amdgcn_s_setprio(0);
    BAR_
    // ---- P3: no reads; stage Bh1(t+1); MFMA (mq0,nq1)
    if (st) STG_B(t + 1, 1);
    GATE4 BAR_
    __builtin_amdgcn_s_setprio(1);
#pragma unroll
    for (int mf = 0; mf < 4; ++mf)
#pragma unroll
      for (int nf = 0; nf < 2; ++nf) {
        acc[0][1][mf][nf] = MFMA16(a0f[mf][0], bf1[nf][0], acc[0][1][mf][nf]);
        acc[0][1][mf][nf] = MFMA16(a0f[mf][1], bf1[nf][1], acc[0][1][mf][nf]);
      }
    __builtin_amdgcn_s_setprio(0);
    BAR_
  }
}

// XCD job-clustering remap (bijective when JP%8==0)
__device__ inline void job_tile(int f, int tilesPerJob, int jp_count,
                                int& jobIdx, int& t) {
  if ((jp_count & 7) == 0) {
    const int xcd = f & 7, slot = f >> 3;
    jobIdx = xcd + 8 * (slot / tilesPerJob);
    t = slot % tilesPerJob;
  } else {
    jobIdx = f / tilesPerJob;
    t = f % tilesPerJob;
  }
}

// ---------------------------------------------------------------------------
// GEMM1 (8-phase): h = GELU_tanh(x @ W1 + b1), bf16 out [JP][512][3072]
// 1D grid 24*JP (=1152 at JP=48); tile t: mt = t/12, nt = t%12.
// ---------------------------------------------------------------------------
__global__ __launch_bounds__(512, 1)
void gemm1_k(const ushort_t* __restrict__ xb, const ushort_t* __restrict__ w1t,
             const float* __restrict__ e_b1, const float* __restrict__ g_b1,
             const int* __restrict__ tidx, ushort_t* __restrict__ h_out,
             int job0, int jp_count) {
  extern __shared__ char sm[];
  int jp, t;
  job_tile(blockIdx.x, 24, jp_count, jp, t);
  const int mt = t / 12, nt = t % 12;
  const int job = job0 + jp;
  const int b = job / 3, s = job - b * 3;
  const int e = (s < 2) ? tidx[b * 2 + s] : E_;
  const char* gA = (const char*)(xb + ((size_t)b * L_ + mt * 256) * D_);
  const char* gB = (const char*)(w1t + ((size_t)e * DFF_ + nt * 256) * D_);
  accfrag_t acc[2][2][4][2] = {};
  gemm8p<12>(gA, gB, sm, acc);

  const float* b1 = (s < 2) ? (e_b1 + (size_t)e * DFF_) : g_b1;
  const int lane = threadIdx.x & 63, w = threadIdx.x >> 6;
  const int wm = (w >> 2) & 1, wn = w & 3;
  ushort_t* hj = h_out + (size_t)jp * L_ * DFF_;
#pragma unroll
  for (int mq = 0; mq < 2; ++mq)
#pragma unroll
    for (int nq = 0; nq < 2; ++nq)
#pragma unroll
      for (int nf = 0; nf < 2; ++nf) {
        const int col = nt * 256 + nq * 128 + wn * 32 + nf * 16 + (lane & 15);
        const float bias = b1[col];
#pragma unroll
        for (int mf = 0; mf < 4; ++mf)
#pragma unroll
          for (int r = 0; r < 4; ++r) {
            const int row = mt * 256 + mq * 128 + wm * 64 + mf * 16 +
                            ((lane >> 4) << 2) + r;
            float v = acc[mq][nq][mf][nf][r] + bias;
            float u = 0.7978845608028654f * (v + 0.044715f * v * v * v);
            float th = 1.0f - 2.0f / (1.0f + __expf(2.0f * u));  // tanh(u)
            hj[(size_t)row * DFF_ + col] = f2bf(0.5f * v * (1.0f + th));
          }
      }
}

// ---------------------------------------------------------------------------
// GEMM2 (r14 structure, proven 151us, exact 1 round): 128x192 tile, BK=64,
// 4 waves, 40KB LDS, 3 blocks/CU.  o = h @ W2 + b2 + x.
// ---------------------------------------------------------------------------
template <int KT>
__device__ __forceinline__ void gemm_body(const char* gA, const char* gB,
                                          char* sm, accfrag_t acc[4][6]) {
  const int tid = threadIdx.x;
  const int lane = tid & 63;
  const int w = tid >> 6, wm = w >> 1, wn = w & 1;
  const int LDB = KT * 128;

  const int R0 = tid >> 3;
  const int swz = (((tid & 7) ^ (R0 & 7)) << 4);
  const char* srcA = gA + (size_t)R0 * LDB + swz;
  const char* srcB = gB + (size_t)R0 * LDB + swz;
  const int dl = tid * 16;

  const int l15 = lane & 15, l7 = lane & 7, lhi = lane >> 4;
  const int a0 = (wm * 64 + l15) * 128 + ((lhi ^ l7) << 4);
  const int a1 = (wm * 64 + l15) * 128 + (((4 + lhi) ^ l7) << 4);
  const int b0 = 16384 + (wn * 96 + l15) * 128 + ((lhi ^ l7) << 4);
  const int b1 = 16384 + (wn * 96 + l15) * 128 + (((4 + lhi) ^ l7) << 4);

#pragma unroll 1
  for (int t = 0; t < KT; ++t) {
    const size_t ko = (size_t)t * 128;
#pragma unroll
    for (int j = 0; j < 4; ++j)
      gload16(srcA + (size_t)j * 32 * LDB + ko, sm + j * 4096 + dl);
#pragma unroll
    for (int j = 0; j < 6; ++j)
      gload16(srcB + (size_t)j * 32 * LDB + ko, sm + 16384 + j * 4096 + dl);
    __syncthreads();
    {
      bfrag_t af[4], bf[6];
#pragma unroll
      for (int nf = 0; nf < 6; ++nf) bf[nf] = *(const bfrag_t*)(sm + b0 + nf * 2048);
#pragma unroll
      for (int mf = 0; mf < 4; ++mf) af[mf] = *(const bfrag_t*)(sm + a0 + mf * 2048);
      __builtin_amdgcn_s_setprio(1);
#pragma unroll
      for (int mf = 0; mf < 4; ++mf)
#pragma unroll
        for (int nf = 0; nf < 6; ++nf)
          acc[mf][nf] = MFMA16(af[mf], bf[nf], acc[mf][nf]);
      __builtin_amdgcn_s_setprio(0);
    }
    __builtin_amdgcn_sched_barrier(0);
    {
      bfrag_t af[4], bf[6];
#pragma unroll
      for (int nf = 0; nf < 6; ++nf) bf[nf] = *(const bfrag_t*)(sm + b1 + nf * 2048);
#pragma unroll
      for (int mf = 0; mf < 4; ++mf) af[mf] = *(const bfrag_t*)(sm + a1 + mf * 2048);
      __builtin_amdgcn_s_setprio(1);
#pragma unroll
      for (int mf = 0; mf < 4; ++mf)
#pragma unroll
        for (int nf = 0; nf < 6; ++nf)
          acc[mf][nf] = MFMA16(af[mf], bf[nf], acc[mf][nf]);
      __builtin_amdgcn_s_setprio(0);
    }
    __syncthreads();
  }
}

__global__ __launch_bounds__(256, 3)
void gemm2_k(const ushort_t* __restrict__ h_in, const ushort_t* __restrict__ w2t,
             const float* __restrict__ e_b2, const float* __restrict__ g_b2,
             const float* __restrict__ x_f, const int* __restrict__ tidx,
             ushort_t* __restrict__ slot_o, float* __restrict__ outp,
             int job0, int jp_count) {
  __shared__ char sm[40960];
  int jp, t;
  job_tile(blockIdx.x, 16, jp_count, jp, t);
  const int mt = t >> 2, nt = t & 3;
  const int job = job0 + jp;
  const int b = job / 3, s = job - b * 3;
  const int e = (s < 2) ? tidx[b * 2 + s] : E_;
  const char* gA = (const char*)(h_in + ((size_t)jp * L_ + mt * 128) * DFF_);
  const char* gB = (const char*)(w2t + ((size_t)e * D_ + nt * 192) * DFF_);
  accfrag_t acc[4][6] = {};
  gemm_body<48>(gA, gB, sm, acc);

  const float* b2 = (s < 2) ? (e_b2 + (size_t)e * D_) : g_b2;
  const int lane = threadIdx.x & 63, w = threadIdx.x >> 6;
  const int wm = w >> 1, wn = w & 1;
  const int row0 = mt * 128 + wm * 64 + ((lane >> 4) << 2);
  const int col0 = nt * 192 + wn * 96 + (lane & 15);
  float bias[6];
#pragma unroll
  for (int nf = 0; nf < 6; ++nf) bias[nf] = b2[col0 + nf * 16];
#pragma unroll
  for (int mf = 0; mf < 4; ++mf)
#pragma unroll
    for (int r = 0; r < 4; ++r) {
      const int row = row0 + mf * 16 + r;
      const float* xr = x_f + ((size_t)b * L_ + row) * D_ + col0;
#pragma unroll
      for (int nf = 0; nf < 6; ++nf) {
        float v = acc[mf][nf][r] + bias[nf] + xr[nf * 16];
        if (s < 2)
          slot_o[(((size_t)b * 2 + s) * L_ + row) * D_ + col0 + nf * 16] = f2bf(v);
        else
          outp[((size_t)b * L_ + row) * D_ + col0 + nf * 16] = v;
      }
    }
}

// ---------------------------------------------------------------------------
// Weight transpose + f32->bf16: src [R][C] f32 -> dst [9][C][R] bf16.
// ---------------------------------------------------------------------------
__global__ __launch_bounds__(256)
void transpose_cvt_k(const float* __restrict__ srcE, const float* __restrict__ srcG,
                     ushort_t* __restrict__ dst, int R, int C) {
  const int z = blockIdx.z;
  const float* src = (z < 8) ? (srcE + (size_t)z * R * C) : srcG;
  ushort_t* out = dst + (size_t)z * R * C;
  __shared__ float tile[64][65];
  const int c0 = blockIdx.x * 64, r0 = blockIdx.y * 64;
  const int t = threadIdx.x;
  const int rr = t >> 4, cc = (t & 15) * 4;
#pragma unroll
  for (int i = 0; i < 4; ++i) {
    const float4 v = *(const float4*)(src + (size_t)(r0 + rr + i * 16) * C + c0 + cc);
    tile[rr + i * 16][cc] = v.x; tile[rr + i * 16][cc + 1] = v.y;
    tile[rr + i * 16][cc + 2] = v.z; tile[rr + i * 16][cc + 3] = v.w;
  }
  __syncthreads();
  const int c = t >> 2, r8 = (t & 3) * 16;
#pragma unroll
  for (int j = 0; j < 2; ++j) {
    ushort_t u[8];
#pragma unroll
    for (int k = 0; k < 8; ++k) u[k] = f2bf(tile[r8 + j * 8 + k][c]);
    *(uint4*)(out + (size_t)(c0 + c) * R + r0 + r8 + j * 8) = *(const uint4*)u;
  }
}

__global__ void cvt_x_k(const float* __restrict__ in, ushort_t* __restrict__ out) {
  const int i = (blockIdx.x * 256 + threadIdx.x) * 4;
  const float4 v = *(const float4*)(in + i);
  uint2 u;
  u.x = (uint32_t)f2bf(v.x) | ((uint32_t)f2bf(v.y) << 16);
  u.y = (uint32_t)f2bf(v.z) | ((uint32_t)f2bf(v.w) << 16);
  *(uint2*)(out + i) = u;
}

// ---------------------------------------------------------------------------
// Router
// ---------------------------------------------------------------------------
__global__ __launch_bounds__(256)
void router_partial_k(const float* __restrict__ emb, const float* __restrict__ We,
                      float* __restrict__ rp) {
  const int nt = blockIdx.x, kb = blockIdx.y;  // 12 x 16
  const int tid = threadIdx.x;
  __shared__ float semb[B_][256];
  const int k0 = kb * 256;
#pragma unroll
  for (int r = 0; r < B_; ++r) semb[r][tid] = emb[(size_t)r * DLLM_ + k0 + tid];
  __syncthreads();
  const int f = nt * 256 + tid;
  float acc[B_] = {};
  for (int k = 0; k < 256; ++k) {
    const float wv = We[(size_t)(k0 + k) * DFF_ + f];
#pragma unroll
    for (int j = 0; j < B_; ++j) acc[j] += semb[j][k] * wv;
  }
#pragma unroll
  for (int j = 0; j < B_; ++j)
    rp[((size_t)kb * B_ + j) * DFF_ + f] = acc[j];
}

__global__ __launch_bounds__(256)
void router_final_k(const float* __restrict__ rp, const float* __restrict__ cyc,
                    const float* __restrict__ Wc, const float* __restrict__ gb,
                    const float* __restrict__ Wo, const float* __restrict__ bo,
                    int* __restrict__ tidx, float* __restrict__ gates) {
  const int b = blockIdx.x, tid = threadIdx.x;
  const float cycb = cyc[b];
  float acc[E_] = {};
#pragma unroll
  for (int fi = 0; fi < 12; ++fi) {
    const int f = tid + fi * 256;
    float sv = 0.0f;
#pragma unroll
    for (int kb = 0; kb < 16; ++kb)
      sv += rp[((size_t)kb * B_ + b) * DFF_ + f];
    sv += cycb * Wc[f] + gb[f];
    sv = fmaxf(sv, 0.0f);
#pragma unroll
    for (int o = 0; o < E_; ++o) acc[o] += sv * Wo[(size_t)f * E_ + o];
  }
  __shared__ float lred[E_][4];
#pragma unroll
  for (int o = 0; o < E_; ++o) {
    float v = acc[o];
#pragma unroll
    for (int off = 32; off > 0; off >>= 1) v += __shfl_down(v, off, 64);
    if ((tid & 63) == 0) lred[o][tid >> 6] = v;
  }
  __syncthreads();
  if (tid == 0) {
    float lg[E_];
    float mx = -1e30f;
    for (int o = 0; o < E_; ++o) {
      lg[o] = lred[o][0] + lred[o][1] + lred[o][2] + lred[o][3] + bo[o];
      mx = fmaxf(mx, lg[o]);
    }
    int i1 = 0;
    for (int o = 1; o < E_; ++o) if (lg[o] > lg[i1]) i1 = o;
    int i2 = (i1 == 0) ? 1 : 0;
    for (int o = 0; o < E_; ++o) if (o != i1 && lg[o] > lg[i2]) i2 = o;
    float p[E_], sum = 0.0f;
    for (int o = 0; o < E_; ++o) { p[o] = __expf(lg[o] - mx); sum += p[o]; }
    const float p1 = p[i1] / sum, p2 = p[i2] / sum;
    const float den = p1 + p2 + 1e-9f;
    tidx[b * 2] = i1; tidx[b * 2 + 1] = i2;
    gates[b * 2] = p1 / den; gates[b * 2 + 1] = p2 / den;
  }
}

// ---------------------------------------------------------------------------
// Final: 3-way LayerNorm + gating + bf16 cast of combined; f32 output.
// ---------------------------------------------------------------------------
__global__ __launch_bounds__(256)
void final_ln_k(float* __restrict__ outp, const ushort_t* __restrict__ so,
                const float* __restrict__ gates, const int* __restrict__ tidx,
                const float* __restrict__ e_gam, const float* __restrict__ e_bet,
                const float* __restrict__ g_gam, const float* __restrict__ g_bet) {
  const int row = blockIdx.x;
  const int b = row >> 9, l = row & 511;
  const int tid = threadIdx.x;
  __shared__ float red4[4];
  float* gr = outp + (size_t)row * D_;
  const ushort_t* s0 = so + (((size_t)b * 2 + 0) * L_ + l) * D_;
  const ushort_t* s1 = so + (((size_t)b * 2 + 1) * L_ + l) * D_;
  float a0[3], a1[3], a2[3];
#pragma unroll
  for (int j = 0; j < 3; ++j) {
    const int d = tid + j * 256;
    a0[j] = gr[d];
    a1[j] = bf2f(s0[d]);
    a2[j] = bf2f(s1[d]);
  }
  auto bsum = [&](float v) -> float {
#pragma unroll
    for (int o = 32; o > 0; o >>= 1) v += __shfl_down(v, o, 64);
    if ((tid & 63) == 0) red4[tid >> 6] = v;
    __syncthreads();
    const float r = red4[0] + red4[1] + red4[2] + red4[3];
    __syncthreads();
    return r;
  };
  const float sg = bsum(a0[0] + a0[1] + a0[2]);
  const float qg = bsum(a0[0] * a0[0] + a0[1] * a0[1] + a0[2] * a0[2]);
  const float s0s = bsum(a1[0] + a1[1] + a1[2]);
  const float q0s = bsum(a1[0] * a1[0] + a1[1] * a1[1] + a1[2] * a1[2]);
  const float s1s = bsum(a2[0] + a2[1] + a2[2]);
  const float q1s = bsum(a2[0] * a2[0] + a2[1] * a2[1] + a2[2] * a2[2]);
  const float inv = 1.0f / 768.0f;
  const float mug = sg * inv, rg = rsqrtf(qg * inv - mug * mug + 1e-5f);
  const float mu0 = s0s * inv, r0 = rsqrtf(q0s * inv - mu0 * mu0 + 1e-5f);
  const float mu1 = s1s * inv, r1 = rsqrtf(q1s * inv - mu1 * mu1 + 1e-5f);
  const int e0 = tidx[b * 2], e1 = tidx[b * 2 + 1];
  const float g0 = gates[b * 2], g1 = gates[b * 2 + 1];
#pragma unroll
  for (int j = 0; j < 3; ++j) {
    const int d = tid + j * 256;
    const float lng = (a0[j] - mug) * rg * g_gam[d] + g_bet[d];
    const float ln0 = (a1[j] - mu0) * r0 * e_gam[(size_t)e0 * D_ + d] + e_bet[(size_t)e0 * D_ + d];
    const float ln1 = (a2[j] - mu1) * r1 * e_gam[(size_t)e1 * D_ + d] + e_bet[(size_t)e1 * D_ + d];
    const float comb = g0 * ln0 + g1 * ln1;
    gr[d] = lng + bf2f(f2bf(comb));
  }
}

// ---------------------------------------------------------------------------
extern "C" void kernel_launch(void* const* d_in, const int* in_sizes, int n_in,
                              void* d_out, int out_size, void* d_ws, size_t ws_size,
                              hipStream_t stream) {
  const float* x_f  = (const float*)d_in[0];
  const float* cyc  = (const float*)d_in[1];
  const float* emb  = (const float*)d_in[2];
  const float* We   = (const float*)d_in[3];
  const float* Wc   = (const float*)d_in[4];
  const float* gb   = (const float*)d_in[5];
  const float* Wo   = (const float*)d_in[6];
  const float* bo   = (const float*)d_in[7];
  const float* e_w1 = (const float*)d_in[8];
  const float* e_b1 = (const float*)d_in[9];
  const float* e_w2 = (const float*)d_in[10];
  const float* e_b2 = (const float*)d_in[11];
  const float* e_gam = (const float*)d_in[12];
  const float* e_bet = (const float*)d_in[13];
  const float* g_w1 = (const float*)d_in[14];
  const float* g_b1 = (const float*)d_in[15];
  const float* g_w2 = (const float*)d_in[16];
  const float* g_b2 = (const float*)d_in[17];
  const float* g_gam = (const float*)d_in[18];
  const float* g_bet = (const float*)d_in[19];
  float* outp = (float*)d_out;
  char* ws = (char*)d_ws;

  size_t off = 0;
  auto alloc = [&](size_t bytes) { size_t o = off; off = (off + bytes + 255) & ~(size_t)255; return o; };
  const size_t o_idx  = alloc(32 * 4);
  const size_t o_gate = alloc(32 * 4);
  const size_t o_rp   = alloc((size_t)16 * B_ * DFF_ * 4);
  const size_t o_xb   = alloc((size_t)B_ * L_ * D_ * 2);
  const size_t o_w1t  = alloc((size_t)9 * DFF_ * D_ * 2);
  const size_t o_w2t  = alloc((size_t)9 * D_ * DFF_ * 2);
  const size_t o_so   = alloc((size_t)B_ * 2 * L_ * D_ * 2);
  const size_t o_h    = off;

  int JP = 1;
  const int divs[10] = {48, 24, 16, 12, 8, 6, 4, 3, 2, 1};
  for (int k = 0; k < 10; ++k) {
    if (o_h + (size_t)divs[k] * L_ * DFF_ * 2 <= ws_size) { JP = divs[k]; break; }
  }

  ushort_t* xb    = (ushort_t*)(ws + o_xb);
  ushort_t* w1t   = (ushort_t*)(ws + o_w1t);
  ushort_t* w2t   = (ushort_t*)(ws + o_w2t);
  ushort_t* so    = (ushort_t*)(ws + o_so);
  ushort_t* h_ws  = (ushort_t*)(ws + o_h);
  int*      tidx  = (int*)(ws + o_idx);
  float*    gates = (float*)(ws + o_gate);
  float*    rp    = (float*)(ws + o_rp);

  hipFuncSetAttribute((const void*)gemm1_k, hipFuncAttributeMaxDynamicSharedMemorySize, 131072);

  cvt_x_k<<<dim3((B_ * L_ * D_) / 1024), dim3(256), 0, stream>>>(x_f, xb);
  transpose_cvt_k<<<dim3(DFF_ / 64, D_ / 64, 9), dim3(256), 0, stream>>>(e_w1, g_w1, w1t, D_, DFF_);
  transpose_cvt_k<<<dim3(D_ / 64, DFF_ / 64, 9), dim3(256), 0, stream>>>(e_w2, g_w2, w2t, DFF_, D_);
  router_partial_k<<<dim3(12, 16), dim3(256), 0, stream>>>(emb, We, rp);
  router_final_k<<<dim3(16), dim3(256), 0, stream>>>(rp, cyc, Wc, gb, Wo, bo, tidx, gates);

  const int passes = 48 / JP;
  for (int p = 0; p < passes; ++p) {
    gemm1_k<<<dim3(24 * JP), dim3(512), 131072, stream>>>(xb, w1t, e_b1, g_b1, tidx, h_ws, p * JP, JP);
    gemm2_k<<<dim3(16 * JP), dim3(256), 0, stream>>>(h_ws, w2t, e_b2, g_b2, x_f, tidx, so, outp, p * JP, JP);
  }
  final_ln_k<<<dim3(B_ * L_), dim3(256), 0, stream>>>(outp, so, gates, tidx,
                                                      e_gam, e_bet, g_gam, g_bet);
}

// Round 16
// 437.210 us; speedup vs baseline: 1.0621x; 1.0621x over previous
//
#include <hip/hip_runtime.h>
#include <cstdint>

#define B_    16
#define L_    512
#define D_    768
#define DFF_  3072
#define DLLM_ 4096
#define E_    8

typedef unsigned short ushort_t;
typedef __attribute__((ext_vector_type(4))) float accfrag_t;
typedef __attribute__((ext_vector_type(8))) short bfrag_t;

typedef __attribute__((address_space(3))) uint32_t lds_u32;
typedef __attribute__((address_space(1))) uint32_t glb_u32;

__device__ inline void gload16(const void* g, void* l) {
  __builtin_amdgcn_global_load_lds((const glb_u32*)(uintptr_t)g,
                                   (lds_u32*)(uint32_t)(uintptr_t)l, 16, 0, 0);
}

__device__ inline ushort_t f2bf(float f) {
  uint32_t u = __float_as_uint(f);
  return (ushort_t)((u + 0x7FFFu + ((u >> 16) & 1u)) >> 16);  // RNE
}
__device__ inline float bf2f(ushort_t v) { return __uint_as_float(((uint32_t)v) << 16); }

#define MFMA16(a, b, c) __builtin_amdgcn_mfma_f32_16x16x32_bf16(a, b, c, 0, 0, 0)

// ---------------------------------------------------------------------------
// 128(M) x 192(N) tile GEMM, BK=64, 4 waves (2M x 2N, wave tile 64x96),
// 256 threads, single 40KB LDS buffer, 2 barriers/K-step, 3 blocks/CU.
// Session-final configuration (r14, 437us).  Measured laws this satisfies:
//  - per-CU staged-bytes delivery saturates ~16 B/cyc at >=3 resident
//    blocks (r9/r13); GEMM time ~= staged bytes / ~9.8 TB/s (validated
//    r14: gemm1 predicted 151us, measured 154).
//  - 1-blk/CU deep pipelines lose 20-80% (r5/6/7/10/15); >3 blk/CU spills
//    or splits bandwidth (r11/r12/r13).
//  - 128x192 minimizes staged bytes/FLOP among register-feasible tiles and
//    makes both grids exact multiples of the 768-slot capacity.
// Register budget: acc 96 AGPR + 10 frags + addr ~= 156 <= 170 via k-half
// split (r13-proven, no spill).  Swizzle: chunk lc of row r at lc ^ (r&7),
// folded into pre-swizzled global source + ds_read offsets; 0 conflicts.
// ---------------------------------------------------------------------------
template <int KT>  // KT = K/64
__device__ __forceinline__ void gemm_body(const char* gA, const char* gB,
                                          char* sm, accfrag_t acc[4][6]) {
  const int tid = threadIdx.x;
  const int lane = tid & 63;
  const int w = tid >> 6, wm = w >> 1, wn = w & 1;
  const int LDB = KT * 128;  // row stride bytes (= K*2)

  const int R0 = tid >> 3;  // 0..31
  const int swz = (((tid & 7) ^ (R0 & 7)) << 4);
  const char* srcA = gA + (size_t)R0 * LDB + swz;
  const char* srcB = gB + (size_t)R0 * LDB + swz;
  const int dl = tid * 16;

  const int l15 = lane & 15, l7 = lane & 7, lhi = lane >> 4;
  const int a0 = (wm * 64 + l15) * 128 + ((lhi ^ l7) << 4);
  const int a1 = (wm * 64 + l15) * 128 + (((4 + lhi) ^ l7) << 4);
  const int b0 = 16384 + (wn * 96 + l15) * 128 + ((lhi ^ l7) << 4);
  const int b1 = 16384 + (wn * 96 + l15) * 128 + (((4 + lhi) ^ l7) << 4);

#pragma unroll 1
  for (int t = 0; t < KT; ++t) {
    const size_t ko = (size_t)t * 128;
#pragma unroll
    for (int j = 0; j < 4; ++j)  // A: 128 rows
      gload16(srcA + (size_t)j * 32 * LDB + ko, sm + j * 4096 + dl);
#pragma unroll
    for (int j = 0; j < 6; ++j)  // B: 192 rows
      gload16(srcB + (size_t)j * 32 * LDB + ko, sm + 16384 + j * 4096 + dl);
    __syncthreads();
    {  // k-half 0 (k = 0..31)
      bfrag_t af[4], bf[6];
#pragma unroll
      for (int nf = 0; nf < 6; ++nf) bf[nf] = *(const bfrag_t*)(sm + b0 + nf * 2048);
#pragma unroll
      for (int mf = 0; mf < 4; ++mf) af[mf] = *(const bfrag_t*)(sm + a0 + mf * 2048);
      __builtin_amdgcn_s_setprio(1);
#pragma unroll
      for (int mf = 0; mf < 4; ++mf)
#pragma unroll
        for (int nf = 0; nf < 6; ++nf)
          acc[mf][nf] = MFMA16(af[mf], bf[nf], acc[mf][nf]);
      __builtin_amdgcn_s_setprio(0);
    }
    __builtin_amdgcn_sched_barrier(0);  // keep half-1 reads below half-0 MFMAs
    {  // k-half 1 (k = 32..63), same registers
      bfrag_t af[4], bf[6];
#pragma unroll
      for (int nf = 0; nf < 6; ++nf) bf[nf] = *(const bfrag_t*)(sm + b1 + nf * 2048);
#pragma unroll
      for (int mf = 0; mf < 4; ++mf) af[mf] = *(const bfrag_t*)(sm + a1 + mf * 2048);
      __builtin_amdgcn_s_setprio(1);
#pragma unroll
      for (int mf = 0; mf < 4; ++mf)
#pragma unroll
        for (int nf = 0; nf < 6; ++nf)
          acc[mf][nf] = MFMA16(af[mf], bf[nf], acc[mf][nf]);
      __builtin_amdgcn_s_setprio(0);
    }
    __syncthreads();
  }
}

// XCD job-clustering remap (bijective when JP%8==0): physical flat id f runs
// on XCD f%8 [m09]; map so all blocks of a job share one XCD.
__device__ inline void job_tile(int f, int tilesPerJob, int jp_count,
                                int& jobIdx, int& t) {
  if ((jp_count & 7) == 0) {
    const int xcd = f & 7, slot = f >> 3;
    jobIdx = xcd + 8 * (slot / tilesPerJob);
    t = slot % tilesPerJob;
  } else {
    jobIdx = f / tilesPerJob;
    t = f % tilesPerJob;
  }
}

// ---------------------------------------------------------------------------
// GEMM1: h = GELU_tanh(x @ W1 + b1), bf16 out [JP][512][3072]
// 1D grid 64*JP (= 3072 at JP=48 -> exactly 4.0 rounds of 768 slots).
// tile t: mt = t>>4 (A-panel-major), nt = t&15 (N tiles of 192).
// ---------------------------------------------------------------------------
__global__ __launch_bounds__(256, 3)
void gemm1_k(const ushort_t* __restrict__ xb, const ushort_t* __restrict__ w1t,
             const float* __restrict__ e_b1, const float* __restrict__ g_b1,
             const int* __restrict__ tidx, ushort_t* __restrict__ h_out,
             int job0, int jp_count) {
  __shared__ char sm[40960];
  int jp, t;
  job_tile(blockIdx.x, 64, jp_count, jp, t);
  const int mt = t >> 4, nt = t & 15;
  const int job = job0 + jp;
  const int b = job / 3, s = job - b * 3;
  const int e = (s < 2) ? tidx[b * 2 + s] : E_;
  const char* gA = (const char*)(xb + ((size_t)b * L_ + mt * 128) * D_);
  const char* gB = (const char*)(w1t + ((size_t)e * DFF_ + nt * 192) * D_);
  accfrag_t acc[4][6] = {};
  gemm_body<12>(gA, gB, sm, acc);

  const float* b1 = (s < 2) ? (e_b1 + (size_t)e * DFF_) : g_b1;
  const int lane = threadIdx.x & 63, w = threadIdx.x >> 6;
  const int wm = w >> 1, wn = w & 1;
  const int row0 = mt * 128 + wm * 64 + ((lane >> 4) << 2);
  const int col0 = nt * 192 + wn * 96 + (lane & 15);
  float bias[6];
#pragma unroll
  for (int nf = 0; nf < 6; ++nf) bias[nf] = b1[col0 + nf * 16];
  ushort_t* hp = h_out + (size_t)jp * L_ * DFF_ + (size_t)row0 * DFF_ + col0;
#pragma unroll
  for (int mf = 0; mf < 4; ++mf)
#pragma unroll
    for (int r = 0; r < 4; ++r) {
      ushort_t* hr_ = hp + (size_t)(mf * 16 + r) * DFF_;
#pragma unroll
      for (int nf = 0; nf < 6; ++nf) {
        float v = acc[mf][nf][r] + bias[nf];
        float u = 0.7978845608028654f * (v + 0.044715f * v * v * v);
        float th = 1.0f - 2.0f / (1.0f + __expf(2.0f * u));  // tanh(u)
        hr_[nf * 16] = f2bf(0.5f * v * (1.0f + th));
      }
    }
}

// ---------------------------------------------------------------------------
// GEMM2: o = h @ W2 + b2 + x.  s<2 -> bf16 slot buffer; s==2 -> f32 d_out.
// 1D grid 16*JP (= 768 at JP=48 -> exactly 1.0 round, no tail).
// tile t: mt = t>>2, nt = t&3 (N tiles of 192).
// ---------------------------------------------------------------------------
__global__ __launch_bounds__(256, 3)
void gemm2_k(const ushort_t* __restrict__ h_in, const ushort_t* __restrict__ w2t,
             const float* __restrict__ e_b2, const float* __restrict__ g_b2,
             const float* __restrict__ x_f, const int* __restrict__ tidx,
             ushort_t* __restrict__ slot_o, float* __restrict__ outp,
             int job0, int jp_count) {
  __shared__ char sm[40960];
  int jp, t;
  job_tile(blockIdx.x, 16, jp_count, jp, t);
  const int mt = t >> 2, nt = t & 3;
  const int job = job0 + jp;
  const int b = job / 3, s = job - b * 3;
  const int e = (s < 2) ? tidx[b * 2 + s] : E_;
  const char* gA = (const char*)(h_in + ((size_t)jp * L_ + mt * 128) * DFF_);
  const char* gB = (const char*)(w2t + ((size_t)e * D_ + nt * 192) * DFF_);
  accfrag_t acc[4][6] = {};
  gemm_body<48>(gA, gB, sm, acc);

  const float* b2 = (s < 2) ? (e_b2 + (size_t)e * D_) : g_b2;
  const int lane = threadIdx.x & 63, w = threadIdx.x >> 6;
  const int wm = w >> 1, wn = w & 1;
  const int row0 = mt * 128 + wm * 64 + ((lane >> 4) << 2);
  const int col0 = nt * 192 + wn * 96 + (lane & 15);
  float bias[6];
#pragma unroll
  for (int nf = 0; nf < 6; ++nf) bias[nf] = b2[col0 + nf * 16];
#pragma unroll
  for (int mf = 0; mf < 4; ++mf)
#pragma unroll
    for (int r = 0; r < 4; ++r) {
      const int row = row0 + mf * 16 + r;
      const float* xr = x_f + ((size_t)b * L_ + row) * D_ + col0;
#pragma unroll
      for (int nf = 0; nf < 6; ++nf) {
        float v = acc[mf][nf][r] + bias[nf] + xr[nf * 16];
        if (s < 2)
          slot_o[(((size_t)b * 2 + s) * L_ + row) * D_ + col0 + nf * 16] = f2bf(v);
        else
          outp[((size_t)b * L_ + row) * D_ + col0 + nf * 16] = v;
      }
    }
}

// ---------------------------------------------------------------------------
// Weight transpose + f32->bf16: src [R][C] f32 (8 experts + general)
// -> dst [9][C][R] bf16.  64x64 tiles; out[c][r] = tile[r][c].
// ---------------------------------------------------------------------------
__global__ __launch_bounds__(256)
void transpose_cvt_k(const float* __restrict__ srcE, const float* __restrict__ srcG,
                     ushort_t* __restrict__ dst, int R, int C) {
  const int z = blockIdx.z;
  const float* src = (z < 8) ? (srcE + (size_t)z * R * C) : srcG;
  ushort_t* out = dst + (size_t)z * R * C;
  __shared__ float tile[64][65];
  const int c0 = blockIdx.x * 64, r0 = blockIdx.y * 64;
  const int t = threadIdx.x;
  const int rr = t >> 4, cc = (t & 15) * 4;
#pragma unroll
  for (int i = 0; i < 4; ++i) {
    const float4 v = *(const float4*)(src + (size_t)(r0 + rr + i * 16) * C + c0 + cc);
    tile[rr + i * 16][cc] = v.x; tile[rr + i * 16][cc + 1] = v.y;
    tile[rr + i * 16][cc + 2] = v.z; tile[rr + i * 16][cc + 3] = v.w;
  }
  __syncthreads();
  const int c = t >> 2, r8 = (t & 3) * 16;
#pragma unroll
  for (int j = 0; j < 2; ++j) {
    ushort_t u[8];
#pragma unroll
    for (int k = 0; k < 8; ++k) u[k] = f2bf(tile[r8 + j * 8 + k][c]);
    *(uint4*)(out + (size_t)(c0 + c) * R + r0 + r8 + j * 8) = *(const uint4*)u;
  }
}

__global__ void cvt_x_k(const float* __restrict__ in, ushort_t* __restrict__ out) {
  const int i = (blockIdx.x * 256 + threadIdx.x) * 4;
  const float4 v = *(const float4*)(in + i);
  uint2 u;
  u.x = (uint32_t)f2bf(v.x) | ((uint32_t)f2bf(v.y) << 16);
  u.y = (uint32_t)f2bf(v.z) | ((uint32_t)f2bf(v.w) << 16);
  *(uint2*)(out + i) = u;
}

// ---------------------------------------------------------------------------
// Router stage 1: partial sums of relu-input (split-K over DLLM)
// ---------------------------------------------------------------------------
__global__ __launch_bounds__(256)
void router_partial_k(const float* __restrict__ emb, const float* __restrict__ We,
                      float* __restrict__ rp) {
  const int nt = blockIdx.x, kb = blockIdx.y;  // 12 x 16
  const int tid = threadIdx.x;
  __shared__ float semb[B_][256];
  const int k0 = kb * 256;
#pragma unroll
  for (int r = 0; r < B_; ++r) semb[r][tid] = emb[(size_t)r * DLLM_ + k0 + tid];
  __syncthreads();
  const int f = nt * 256 + tid;
  float acc[B_] = {};
  for (int k = 0; k < 256; ++k) {
    const float wv = We[(size_t)(k0 + k) * DFF_ + f];
#pragma unroll
    for (int j = 0; j < B_; ++j) acc[j] += semb[j][k] * wv;
  }
#pragma unroll
  for (int j = 0; j < B_; ++j)
    rp[((size_t)kb * B_ + j) * DFF_ + f] = acc[j];
}

// ---------------------------------------------------------------------------
// Router stage 2 (merged reduce + final): per batch b, reduce partials ->
// relu -> logits = h @ Wo + bo -> top2 + renormalized gates.
// ---------------------------------------------------------------------------
__global__ __launch_bounds__(256)
void router_final_k(const float* __restrict__ rp, const float* __restrict__ cyc,
                    const float* __restrict__ Wc, const float* __restrict__ gb,
                    const float* __restrict__ Wo, const float* __restrict__ bo,
                    int* __restrict__ tidx, float* __restrict__ gates) {
  const int b = blockIdx.x, tid = threadIdx.x;
  const float cycb = cyc[b];
  float acc[E_] = {};
#pragma unroll
  for (int fi = 0; fi < 12; ++fi) {
    const int f = tid + fi * 256;
    float sv = 0.0f;
#pragma unroll
    for (int kb = 0; kb < 16; ++kb)
      sv += rp[((size_t)kb * B_ + b) * DFF_ + f];
    sv += cycb * Wc[f] + gb[f];
    sv = fmaxf(sv, 0.0f);
#pragma unroll
    for (int o = 0; o < E_; ++o) acc[o] += sv * Wo[(size_t)f * E_ + o];
  }
  __shared__ float lred[E_][4];
#pragma unroll
  for (int o = 0; o < E_; ++o) {
    float v = acc[o];
#pragma unroll
    for (int off = 32; off > 0; off >>= 1) v += __shfl_down(v, off, 64);
    if ((tid & 63) == 0) lred[o][tid >> 6] = v;
  }
  __syncthreads();
  if (tid == 0) {
    float lg[E_];
    float mx = -1e30f;
    for (int o = 0; o < E_; ++o) {
      lg[o] = lred[o][0] + lred[o][1] + lred[o][2] + lred[o][3] + bo[o];
      mx = fmaxf(mx, lg[o]);
    }
    int i1 = 0;
    for (int o = 1; o < E_; ++o) if (lg[o] > lg[i1]) i1 = o;
    int i2 = (i1 == 0) ? 1 : 0;
    for (int o = 0; o < E_; ++o) if (o != i1 && lg[o] > lg[i2]) i2 = o;
    float p[E_], sum = 0.0f;
    for (int o = 0; o < E_; ++o) { p[o] = __expf(lg[o] - mx); sum += p[o]; }
    const float p1 = p[i1] / sum, p2 = p[i2] / sum;
    const float den = p1 + p2 + 1e-9f;
    tidx[b * 2] = i1; tidx[b * 2 + 1] = i2;
    gates[b * 2] = p1 / den; gates[b * 2 + 1] = p2 / den;
  }
}

// ---------------------------------------------------------------------------
// Final: 3-way LayerNorm + gating + bf16 cast of combined; f32 output.
// ---------------------------------------------------------------------------
__global__ __launch_bounds__(256)
void final_ln_k(float* __restrict__ outp, const ushort_t* __restrict__ so,
                const float* __restrict__ gates, const int* __restrict__ tidx,
                const float* __restrict__ e_gam, const float* __restrict__ e_bet,
                const float* __restrict__ g_gam, const float* __restrict__ g_bet) {
  const int row = blockIdx.x;
  const int b = row >> 9, l = row & 511;
  const int tid = threadIdx.x;
  __shared__ float red4[4];
  float* gr = outp + (size_t)row * D_;
  const ushort_t* s0 = so + (((size_t)b * 2 + 0) * L_ + l) * D_;
  const ushort_t* s1 = so + (((size_t)b * 2 + 1) * L_ + l) * D_;
  float a0[3], a1[3], a2[3];
#pragma unroll
  for (int j = 0; j < 3; ++j) {
    const int d = tid + j * 256;
    a0[j] = gr[d];
    a1[j] = bf2f(s0[d]);
    a2[j] = bf2f(s1[d]);
  }
  auto bsum = [&](float v) -> float {
#pragma unroll
    for (int o = 32; o > 0; o >>= 1) v += __shfl_down(v, o, 64);
    if ((tid & 63) == 0) red4[tid >> 6] = v;
    __syncthreads();
    const float r = red4[0] + red4[1] + red4[2] + red4[3];
    __syncthreads();
    return r;
  };
  const float sg = bsum(a0[0] + a0[1] + a0[2]);
  const float qg = bsum(a0[0] * a0[0] + a0[1] * a0[1] + a0[2] * a0[2]);
  const float s0s = bsum(a1[0] + a1[1] + a1[2]);
  const float q0s = bsum(a1[0] * a1[0] + a1[1] * a1[1] + a1[2] * a1[2]);
  const float s1s = bsum(a2[0] + a2[1] + a2[2]);
  const float q1s = bsum(a2[0] * a2[0] + a2[1] * a2[1] + a2[2] * a2[2]);
  const float inv = 1.0f / 768.0f;
  const float mug = sg * inv, rg = rsqrtf(qg * inv - mug * mug + 1e-5f);
  const float mu0 = s0s * inv, r0 = rsqrtf(q0s * inv - mu0 * mu0 + 1e-5f);
  const float mu1 = s1s * inv, r1 = rsqrtf(q1s * inv - mu1 * mu1 + 1e-5f);
  const int e0 = tidx[b * 2], e1 = tidx[b * 2 + 1];
  const float g0 = gates[b * 2], g1 = gates[b * 2 + 1];
#pragma unroll
  for (int j = 0; j < 3; ++j) {
    const int d = tid + j * 256;
    const float lng = (a0[j] - mug) * rg * g_gam[d] + g_bet[d];
    const float ln0 = (a1[j] - mu0) * r0 * e_gam[(size_t)e0 * D_ + d] + e_bet[(size_t)e0 * D_ + d];
    const float ln1 = (a2[j] - mu1) * r1 * e_gam[(size_t)e1 * D_ + d] + e_bet[(size_t)e1 * D_ + d];
    const float comb = g0 * ln0 + g1 * ln1;
    gr[d] = lng + bf2f(f2bf(comb));
  }
}

// ---------------------------------------------------------------------------
extern "C" void kernel_launch(void* const* d_in, const int* in_sizes, int n_in,
                              void* d_out, int out_size, void* d_ws, size_t ws_size,
                              hipStream_t stream) {
  const float* x_f  = (const float*)d_in[0];
  const float* cyc  = (const float*)d_in[1];
  const float* emb  = (const float*)d_in[2];
  const float* We   = (const float*)d_in[3];
  const float* Wc   = (const float*)d_in[4];
  const float* gb   = (const float*)d_in[5];
  const float* Wo   = (const float*)d_in[6];
  const float* bo   = (const float*)d_in[7];
  const float* e_w1 = (const float*)d_in[8];
  const float* e_b1 = (const float*)d_in[9];
  const float* e_w2 = (const float*)d_in[10];
  const float* e_b2 = (const float*)d_in[11];
  const float* e_gam = (const float*)d_in[12];
  const float* e_bet = (const float*)d_in[13];
  const float* g_w1 = (const float*)d_in[14];
  const float* g_b1 = (const float*)d_in[15];
  const float* g_w2 = (const float*)d_in[16];
  const float* g_b2 = (const float*)d_in[17];
  const float* g_gam = (const float*)d_in[18];
  const float* g_bet = (const float*)d_in[19];
  float* outp = (float*)d_out;
  char* ws = (char*)d_ws;

  size_t off = 0;
  auto alloc = [&](size_t bytes) { size_t o = off; off = (off + bytes + 255) & ~(size_t)255; return o; };
  const size_t o_idx  = alloc(32 * 4);
  const size_t o_gate = alloc(32 * 4);
  const size_t o_rp   = alloc((size_t)16 * B_ * DFF_ * 4);
  const size_t o_xb   = alloc((size_t)B_ * L_ * D_ * 2);
  const size_t o_w1t  = alloc((size_t)9 * DFF_ * D_ * 2);
  const size_t o_w2t  = alloc((size_t)9 * D_ * DFF_ * 2);
  const size_t o_so   = alloc((size_t)B_ * 2 * L_ * D_ * 2);
  const size_t o_h    = off;

  int JP = 1;
  const int divs[10] = {48, 24, 16, 12, 8, 6, 4, 3, 2, 1};
  for (int k = 0; k < 10; ++k) {
    if (o_h + (size_t)divs[k] * L_ * DFF_ * 2 <= ws_size) { JP = divs[k]; break; }
  }

  ushort_t* xb    = (ushort_t*)(ws + o_xb);
  ushort_t* w1t   = (ushort_t*)(ws + o_w1t);
  ushort_t* w2t   = (ushort_t*)(ws + o_w2t);
  ushort_t* so    = (ushort_t*)(ws + o_so);
  ushort_t* h_ws  = (ushort_t*)(ws + o_h);
  int*      tidx  = (int*)(ws + o_idx);
  float*    gates = (float*)(ws + o_gate);
  float*    rp    = (float*)(ws + o_rp);

  cvt_x_k<<<dim3((B_ * L_ * D_) / 1024), dim3(256), 0, stream>>>(x_f, xb);
  transpose_cvt_k<<<dim3(DFF_ / 64, D_ / 64, 9), dim3(256), 0, stream>>>(e_w1, g_w1, w1t, D_, DFF_);
  transpose_cvt_k<<<dim3(D_ / 64, DFF_ / 64, 9), dim3(256), 0, stream>>>(e_w2, g_w2, w2t, DFF_, D_);
  router_partial_k<<<dim3(12, 16), dim3(256), 0, stream>>>(emb, We, rp);
  router_final_k<<<dim3(16), dim3(256), 0, stream>>>(rp, cyc, Wc, gb, Wo, bo, tidx, gates);

  const int passes = 48 / JP;
  for (int p = 0; p < passes; ++p) {
    gemm1_k<<<dim3(64 * JP), dim3(256), 0, stream>>>(xb, w1t, e_b1, g_b1, tidx, h_ws, p * JP, JP);
    gemm2_k<<<dim3(16 * JP), dim3(256), 0, stream>>>(h_ws, w2t, e_b2, g_b2, x_f, tidx, so, outp, p * JP, JP);
  }
  final_ln_k<<<dim3(B_ * L_), dim3(256), 0, stream>>>(outp, so, gates, tidx,
                                                      e_gam, e_bet, g_gam, g_bet);
}